// Round 1
// baseline (2410.149 us; speedup 1.0000x reference)
//
#include <hip/hip_runtime.h>
#include <math.h>

#define BATCH   8
#define SEQ     512
#define IN_DIM  32
#define D_MODEL 512
#define N_LAYERS 4
#define D_INNER 1024
#define D_STATE 16
#define D_CONV  4
#define DT_RANK 32
#define NTOK    (BATCH * SEQ)   // 4096

__device__ __forceinline__ float sigmoidf_(float x) { return 1.f / (1.f + __expf(-x)); }

// C[m,n] = act( dot(A[m,0:K], W[n,0:K]) + bias[n] ) + R[m,n]
// A: (M,lda) row-major (uses first K cols), W: (N,K) row-major, C/R: (M,N).
// act: 0 = none, 1 = softplus. 64x64 tile, 256 threads, 4x4 microtile, TK=16.
// Requires M%64==0, N%64==0, K%16==0, lda%4==0, K%4==0.
__global__ __launch_bounds__(256) void gemm_bt64(
    const float* __restrict__ A, int lda,
    const float* __restrict__ W,
    const float* __restrict__ bias,
    const float* __restrict__ R,
    float* __restrict__ C,
    int N, int K, int act)
{
    __shared__ __align__(16) float As[16][64];
    __shared__ __align__(16) float Ws[16][64];
    const int tid = threadIdx.x;
    const int tx = tid & 15, ty = tid >> 4;
    const int m0 = blockIdx.y * 64, n0 = blockIdx.x * 64;
    const int lm = tid >> 2;            // 0..63: tile row loaded by this thread
    const int lk = (tid & 3) * 4;       // 0,4,8,12: k quad

    float acc[4][4] = {};
    for (int k0 = 0; k0 < K; k0 += 16) {
        float4 av = *(const float4*)&A[(size_t)(m0 + lm) * lda + k0 + lk];
        float4 wv = *(const float4*)&W[(size_t)(n0 + lm) * K   + k0 + lk];
        As[lk + 0][lm] = av.x; As[lk + 1][lm] = av.y; As[lk + 2][lm] = av.z; As[lk + 3][lm] = av.w;
        Ws[lk + 0][lm] = wv.x; Ws[lk + 1][lm] = wv.y; Ws[lk + 2][lm] = wv.z; Ws[lk + 3][lm] = wv.w;
        __syncthreads();
        #pragma unroll
        for (int k = 0; k < 16; ++k) {
            float4 a4 = *(const float4*)&As[k][ty * 4];
            float4 b4 = *(const float4*)&Ws[k][tx * 4];
            float a[4] = {a4.x, a4.y, a4.z, a4.w};
            float b[4] = {b4.x, b4.y, b4.z, b4.w};
            #pragma unroll
            for (int i = 0; i < 4; ++i)
                #pragma unroll
                for (int j = 0; j < 4; ++j)
                    acc[i][j] = fmaf(a[i], b[j], acc[i][j]);
        }
        __syncthreads();
    }
    #pragma unroll
    for (int i = 0; i < 4; ++i) {
        const int m = m0 + ty * 4 + i;
        #pragma unroll
        for (int j = 0; j < 4; ++j) {
            const int n = n0 + tx * 4 + j;
            float v = acc[i][j];
            if (bias) v += bias[n];
            if (act == 1) v = (v > 20.f) ? v : log1pf(__expf(v));   // softplus
            if (R) v += R[(size_t)m * N + n];
            C[(size_t)m * N + n] = v;
        }
    }
}

// xn[tok,:] = h[tok,:] * rsqrt(mean(h^2)+1e-5) * w
__global__ __launch_bounds__(256) void rmsnorm_kernel(
    const float* __restrict__ h, const float* __restrict__ w, float* __restrict__ xn)
{
    const int tok = blockIdx.x, tid = threadIdx.x;
    const float* row = h + (size_t)tok * D_MODEL;
    float v0 = row[tid], v1 = row[tid + 256];
    float s = v0 * v0 + v1 * v1;
    #pragma unroll
    for (int off = 32; off > 0; off >>= 1) s += __shfl_down(s, off, 64);
    __shared__ float ss[4];
    if ((tid & 63) == 0) ss[tid >> 6] = s;
    __syncthreads();
    const float total = ss[0] + ss[1] + ss[2] + ss[3];
    const float scale = rsqrtf(total * (1.f / (float)D_MODEL) + 1e-5f);
    float* orow = xn + (size_t)tok * D_MODEL;
    orow[tid]       = v0 * scale * w[tid];
    orow[tid + 256] = v1 * scale * w[tid + 256];
}

// depthwise causal conv (k=4, left pad 3) over xz[:, 0:D_INNER] + bias, then silu
__global__ __launch_bounds__(256) void conv_silu_kernel(
    const float* __restrict__ xz, const float* __restrict__ cw,
    const float* __restrict__ cb, float* __restrict__ xr)
{
    const int idx = blockIdx.x * 256 + threadIdx.x;   // over NTOK*D_INNER
    const int d   = idx & (D_INNER - 1);
    const int tok = idx >> 10;
    const int l   = tok & (SEQ - 1);
    float acc = cb[d];
    #pragma unroll
    for (int k = 0; k < D_CONV; ++k) {
        const int t = l - (D_CONV - 1) + k;
        if (t >= 0)
            acc = fmaf(xz[(size_t)(tok + t - l) * (2 * D_INNER) + d], cw[d * D_CONV + k], acc);
    }
    xr[idx] = acc * sigmoidf_(acc);
}

// selective scan; one thread per (b, d) channel. B/C for the whole batch staged in LDS.
// y[tok,d] = (sum_n h_n * C_n + D[d]*xr) * silu(z);  y may alias xrp (same-index RAW within thread).
__global__ __launch_bounds__(256) void scan_kernel(
    const float* __restrict__ delta, const float* __restrict__ xrp,
    const float* __restrict__ dbc,   const float* __restrict__ xz,
    const float* __restrict__ A_log, const float* __restrict__ Dp,
    float* __restrict__ y)
{
    __shared__ __align__(16) float sBC[SEQ * 32];   // 64 KB: per l, [B0..B15, C0..C15]
    const int b = blockIdx.y;
    const int d = blockIdx.x * 256 + threadIdx.x;
    for (int idx = threadIdx.x; idx < SEQ * 32; idx += 256) {
        const int l = idx >> 5, c = idx & 31;
        sBC[idx] = dbc[((size_t)(b * SEQ + l)) * 64 + 32 + c];
    }
    __syncthreads();

    float A[D_STATE];
    #pragma unroll
    for (int n = 0; n < D_STATE; ++n) A[n] = -__expf(A_log[d * D_STATE + n]);
    const float Dd = Dp[d];
    float hs[D_STATE];
    #pragma unroll
    for (int n = 0; n < D_STATE; ++n) hs[n] = 0.f;

    for (int l = 0; l < SEQ; ++l) {
        const size_t tok = (size_t)b * SEQ + l;
        const float dv = delta[tok * D_INNER + d];
        const float xv = xrp[tok * D_INNER + d];
        const float zv = xz[tok * 2 * D_INNER + D_INNER + d];
        const float dx = dv * xv;
        const float4* p = (const float4*)&sBC[l * 32];
        float acc = 0.f;
        #pragma unroll
        for (int q = 0; q < 4; ++q) {
            const float4 B4 = p[q];
            const float4 C4 = p[4 + q];
            hs[4*q+0] = fmaf(__expf(dv * A[4*q+0]), hs[4*q+0], dx * B4.x); acc = fmaf(hs[4*q+0], C4.x, acc);
            hs[4*q+1] = fmaf(__expf(dv * A[4*q+1]), hs[4*q+1], dx * B4.y); acc = fmaf(hs[4*q+1], C4.y, acc);
            hs[4*q+2] = fmaf(__expf(dv * A[4*q+2]), hs[4*q+2], dx * B4.z); acc = fmaf(hs[4*q+2], C4.z, acc);
            hs[4*q+3] = fmaf(__expf(dv * A[4*q+3]), hs[4*q+3], dx * B4.w); acc = fmaf(hs[4*q+3], C4.w, acc);
        }
        const float yv = acc + Dd * xv;
        y[tok * D_INNER + d] = yv * (zv * sigmoidf_(zv));
    }
}

// d1[b,j] = relu(h[b,last,:] @ w1[j,:] + b1[j]); block per b, thread per j (256)
__global__ __launch_bounds__(256) void dec1_kernel(
    const float* __restrict__ h, const float* __restrict__ w1,
    const float* __restrict__ b1, float* __restrict__ d1)
{
    __shared__ __align__(16) float hr[D_MODEL];
    const int b = blockIdx.x, j = threadIdx.x;
    const float* row = h + ((size_t)(b * SEQ + SEQ - 1)) * D_MODEL;
    hr[j] = row[j];
    hr[j + 256] = row[j + 256];
    __syncthreads();
    float acc = b1[j];
    const float* wr = w1 + (size_t)j * D_MODEL;
    for (int k = 0; k < D_MODEL; k += 4) {
        const float4 wv = *(const float4*)&wr[k];
        const float4 hv = *(const float4*)&hr[k];
        acc = fmaf(wv.x, hv.x, acc); acc = fmaf(wv.y, hv.y, acc);
        acc = fmaf(wv.z, hv.z, acc); acc = fmaf(wv.w, hv.w, acc);
    }
    d1[b * 256 + j] = fmaxf(acc, 0.f);
}

// out[b] = d1[b,:] @ w2 + b2; block per b, 64 threads (1 wave)
__global__ void dec2_kernel(const float* __restrict__ d1, const float* __restrict__ w2,
                            const float* __restrict__ b2, float* __restrict__ out)
{
    const int b = blockIdx.x, t = threadIdx.x;
    float acc = 0.f;
    for (int k = t; k < 256; k += 64) acc = fmaf(d1[b * 256 + k], w2[k], acc);
    #pragma unroll
    for (int off = 32; off > 0; off >>= 1) acc += __shfl_down(acc, off, 64);
    if (t == 0) out[b] = acc + b2[0];
}

extern "C" void kernel_launch(void* const* d_in, const int* in_sizes, int n_in,
                              void* d_out, int out_size, void* d_ws, size_t ws_size,
                              hipStream_t stream)
{
    const float* x      = (const float*)d_in[0];
    const float* enc_w  = (const float*)d_in[1];
    const float* enc_b  = (const float*)d_in[2];
    const float* in_w   = (const float*)d_in[3];
    const float* conv_w = (const float*)d_in[4];
    const float* conv_b = (const float*)d_in[5];
    const float* xp_w   = (const float*)d_in[6];
    const float* dtp_w  = (const float*)d_in[7];
    const float* dtp_b  = (const float*)d_in[8];
    const float* A_log  = (const float*)d_in[9];
    const float* Dp     = (const float*)d_in[10];
    const float* out_w  = (const float*)d_in[11];
    const float* norm_w = (const float*)d_in[12];
    const float* dec_w1 = (const float*)d_in[13];
    const float* dec_b1 = (const float*)d_in[14];
    const float* dec_w2 = (const float*)d_in[15];
    const float* dec_b2 = (const float*)d_in[16];
    float* out = (float*)d_out;

    // workspace layout (floats); y aliases xr (safe: same-index, read-before-write per thread)
    float* ws    = (float*)d_ws;
    float* h     = ws;                                   // NTOK*512   = 2M
    float* xn    = h     + (size_t)NTOK * D_MODEL;       // NTOK*512   = 2M
    float* xz    = xn    + (size_t)NTOK * D_MODEL;       // NTOK*2048  = 8M
    float* xr    = xz    + (size_t)NTOK * 2 * D_INNER;   // NTOK*1024  = 4M
    float* delta = xr    + (size_t)NTOK * D_INNER;       // NTOK*1024  = 4M
    float* dbc   = delta + (size_t)NTOK * D_INNER;       // NTOK*64
    float* d1    = dbc   + (size_t)NTOK * 64;            // 2048

    // encoder: h = x @ enc_w.T + enc_b
    gemm_bt64<<<dim3(D_MODEL / 64, NTOK / 64), 256, 0, stream>>>(
        x, IN_DIM, enc_w, enc_b, nullptr, h, D_MODEL, IN_DIM, 0);

    for (int i = 0; i < N_LAYERS; ++i) {
        rmsnorm_kernel<<<NTOK, 256, 0, stream>>>(h, norm_w + (size_t)i * D_MODEL, xn);

        // xz = xn @ in_proj_w[i].T   (4096 x 2048, K=512)
        gemm_bt64<<<dim3(2 * D_INNER / 64, NTOK / 64), 256, 0, stream>>>(
            xn, D_MODEL, in_w + (size_t)i * 2 * D_INNER * D_MODEL,
            nullptr, nullptr, xz, 2 * D_INNER, D_MODEL, 0);

        // xr = silu(causal_dwconv(xz[:, :D_INNER]) + cb)
        conv_silu_kernel<<<NTOK * D_INNER / 256, 256, 0, stream>>>(
            xz, conv_w + (size_t)i * D_INNER * D_CONV, conv_b + (size_t)i * D_INNER, xr);

        // dbc = xr @ x_proj_w[i].T   (4096 x 64, K=1024)
        gemm_bt64<<<dim3(1, NTOK / 64), 256, 0, stream>>>(
            xr, D_INNER, xp_w + (size_t)i * 64 * D_INNER,
            nullptr, nullptr, dbc, 64, D_INNER, 0);

        // delta = softplus(dbc[:, :32] @ dt_proj_w[i].T + dt_proj_b[i])  (4096 x 1024, K=32)
        gemm_bt64<<<dim3(D_INNER / 64, NTOK / 64), 256, 0, stream>>>(
            dbc, 64, dtp_w + (size_t)i * D_INNER * DT_RANK,
            dtp_b + (size_t)i * D_INNER, nullptr, delta, D_INNER, DT_RANK, 1);

        // selective scan + D skip + silu(z) gate; writes y in-place over xr
        scan_kernel<<<dim3(D_INNER / 256, BATCH), 256, 0, stream>>>(
            delta, xr, dbc, xz,
            A_log + (size_t)i * D_INNER * D_STATE, Dp + (size_t)i * D_INNER, xr);

        // h = h + y @ out_proj_w[i].T   (4096 x 512, K=1024)
        gemm_bt64<<<dim3(D_MODEL / 64, NTOK / 64), 256, 0, stream>>>(
            xr, D_INNER, out_w + (size_t)i * D_MODEL * D_INNER,
            nullptr, h, h, D_MODEL, D_INNER, 0);
    }

    dec1_kernel<<<BATCH, 256, 0, stream>>>(h, dec_w1, dec_b1, d1);
    dec2_kernel<<<BATCH, 64, 0, stream>>>(d1, dec_w2, dec_b2, out);
}